// Round 6
// baseline (609.438 us; speedup 1.0000x reference)
//
#include <hip/hip_runtime.h>

#define LRELU_SLOPE 0.01f
#define NEG_BIG -1e10f

typedef unsigned short ushort_t;
typedef __bf16 bf16x8 __attribute__((ext_vector_type(8)));
typedef float f32x4 __attribute__((ext_vector_type(4)));

static __device__ __forceinline__ float lrelu_f(float x) {
    return x >= 0.0f ? x : LRELU_SLOPE * x;
}

static __device__ __forceinline__ ushort_t f2bf(float f) {
    unsigned int u = __float_as_uint(f);
    u += 0x7fffu + ((u >> 16) & 1u);
    return (ushort_t)(u >> 16);
}

static __device__ __forceinline__ void gld_lds16(const ushort_t* g, ushort_t* l) {
    __builtin_amdgcn_global_load_lds((const __attribute__((address_space(1))) void*)g,
                                     (__attribute__((address_space(3))) void*)l,
                                     16, 0, 0);
}

// ---------------------------------------------------------------------------
// NT bf16 MFMA GEMM: C[m,n] = epi( sum_k A[m,k] * B[n,k] )
// 256x256 tile, 16 waves (4M x 4N, 1024 thr), BK=64; per-wave out 64x64.
// OCCUPANCY redesign (R4 post-mortem): the 8-wave variant held ~232 unified
// regs/wave (104 VGPR + 128 acc) -> HW caps 8 waves/CU (20% occ measured).
// 16 waves x 64x64 needs acc 4x4xf32x4 = 64 regs + 32 frag regs (~115);
// __launch_bounds__(1024,4) caps at 128 -> 16 waves/CU (4/SIMD), 2x TLP.
// Per K-tile T (2 barriers, counted vmcnt, loads in flight across tile):
//   barrier1  (all waves done READING buf^1 in tile T-1 -> safe to overwrite)
//   stage(T+1) into buf^1 (4 gld_lds/wave); vmcnt(4) -> stage-T landed,
//     stage-T+1 stays in flight across the whole tile
//   barrier2  (all waves' stage-T visible)
//   2 k-phases (kk=0: chunks 0..3, kk=1: 4..7): {8 ds_read_b128, lgkmcnt(0),
//     sched_barrier(0), setprio(1), 16 MFMA, setprio(0)}
// Only one kk's frags live at a time -> fits the 128-reg cap.
// LDS XOR-swizzle: row r's 16B-chunk c stored at c ^ (r&7); staging inverse-
// permutes the per-lane GLOBAL source chunk (gld_lds dest linear, rule #21);
// ds_read applies the same XOR => conflict-free frag reads.
// XCD-aware tile remap (R0): lin -> (lin%8)*(nwg/8)+lin/8.
// RM mask: row < Mhalf ? rm1[row] : rm2[row-Mhalf]  (combined-M launches)
// PM mask: rm1[bz*M+row] && rm2[bz*N+col] else += NEG_BIG (batched score GEMM)
// TWOUT: also store bf16 transposed per-batch with slot swap:
//   CT[(((row>>9)+64)&127)*S + col*512 + (row&511)]  -> [r2mT | r1mT] order
// ---------------------------------------------------------------------------
template<bool BIAS, bool LRELU, bool RM, bool PM, bool BF16OUT, bool TWOUT>
__global__ __launch_bounds__(1024, 4)
void gemm_nt(const ushort_t* __restrict__ A0, const ushort_t* __restrict__ A1,
             int Ksplit, int lda0, int lda1,
             const ushort_t* __restrict__ B, int ldb,
             const float* __restrict__ bias,
             const int* __restrict__ rm1, const int* __restrict__ rm2,
             void* __restrict__ C, int ldc,
             ushort_t* __restrict__ CT, int Mhalf,
             int M, int N, int K,
             long sA, long sB, long sC)
{
    __shared__ ushort_t lds[2][2][256 * 64];   // [buf][A/B][row*64 + k]

    // XCD-aware block remap (see header comment)
    const unsigned nbx = gridDim.x, nby = gridDim.y;
    unsigned lin = blockIdx.x + nbx * (blockIdx.y + nby * blockIdx.z);
    const unsigned nwg = nbx * nby * gridDim.z;
    if ((nwg & 7u) == 0u)
        lin = (lin & 7u) * (nwg >> 3) + (lin >> 3);
    const unsigned bxs = lin % nbx;
    const unsigned t1  = lin / nbx;
    const unsigned bys = t1 % nby;
    const unsigned bzs = t1 / nby;

    const int bz   = (int)bzs;
    const int tid  = threadIdx.x;
    const int w    = tid >> 6;         // 0..15
    const int lane = tid & 63;
    const int wm   = w >> 2;           // 0..3  (M quarter)
    const int wn   = w & 3;            // 0..3  (N quarter)
    const int row0 = (int)bys * 256;
    const int col0 = (int)bxs * 256;

    const ushort_t* Ab0 = A0 + (long)bz * sA;
    const ushort_t* Ab1 = A1 + (long)bz * sA;
    const ushort_t* Bb  = B  + (long)bz * sB;

    // staging: wave w covers rows [w*16, w*16+16) of A-tile and B-tile,
    // 2 gld_lds each (8 rows per load; 64 lanes x 16B).
    // per-lane source chunk inverse-swizzled (row%8 == lane>>3).
    const int srr = w * 16 + (lane >> 3);
    const int so  = (((lane & 7) ^ ((lane >> 3) & 7)) * 8);

    // fragment read addressing
    const int lr = lane & 15, q = lane >> 4;
    const int cx0 = ((q ^ (lr & 7)) * 8);          // kk=0 chunk, swizzled
    const int cx1 = (((q + 4) ^ (lr & 7)) * 8);    // kk=1 chunk, swizzled
    const int aRow = (wm * 64 + lr) * 64;
    const int bRow = (wn * 64 + lr) * 64;

    f32x4 acc[4][4] = {};

    auto stage = [&](int T, int buf) {
        const int k0g = T << 6;
        const ushort_t* Ap; int kk0, ldaP;
        if (k0g < Ksplit) { Ap = Ab0; kk0 = k0g;          ldaP = lda0; }
        else              { Ap = Ab1; kk0 = k0g - Ksplit; ldaP = lda1; }
        ushort_t* Ad = &lds[buf][0][0];
        ushort_t* Bd = &lds[buf][1][0];
        #pragma unroll
        for (int u = 0; u < 2; ++u)
            gld_lds16(Ap + (size_t)(row0 + srr + u * 8) * ldaP + kk0 + so,
                      Ad + (w * 16 + u * 8) * 64);
        #pragma unroll
        for (int u = 0; u < 2; ++u)
            gld_lds16(Bb + (size_t)(col0 + srr + u * 8) * ldb + k0g + so,
                      Bd + (w * 16 + u * 8) * 64);
    };

    const int NT = K >> 6;
    stage(0, 0);

    for (int T = 0; T < NT; ++T) {
        const int buf = T & 1;
        const ushort_t* Abuf = &lds[buf][0][0];
        const ushort_t* Bbuf = &lds[buf][1][0];

        // barrier1: everyone finished READING buf^1 (tile T-1) -> overwrite ok
        __builtin_amdgcn_s_barrier();
        asm volatile("" ::: "memory");
        if (T + 1 < NT) {
            stage(T + 1, buf ^ 1);
            // stage-T's 4 landed; stage-T+1's 4 stay in flight across tile
            asm volatile("s_waitcnt vmcnt(4)" ::: "memory");
        } else {
            asm volatile("s_waitcnt vmcnt(0)" ::: "memory");
        }
        // barrier2: all waves' stage-T visible
        __builtin_amdgcn_s_barrier();
        asm volatile("" ::: "memory");

        #pragma unroll
        for (int kk = 0; kk < 2; ++kk) {
            const int cx = kk ? cx1 : cx0;
            bf16x8 af[4], bf[4];
            #pragma unroll
            for (int ii = 0; ii < 4; ++ii)
                af[ii] = *reinterpret_cast<const bf16x8*>(&Abuf[aRow + (ii * 16) * 64 + cx]);
            #pragma unroll
            for (int jj = 0; jj < 4; ++jj)
                bf[jj] = *reinterpret_cast<const bf16x8*>(&Bbuf[bRow + (jj * 16) * 64 + cx]);
            asm volatile("s_waitcnt lgkmcnt(0)" ::: "memory");
            __builtin_amdgcn_sched_barrier(0);
            __builtin_amdgcn_s_setprio(1);
            #pragma unroll
            for (int ii = 0; ii < 4; ++ii)
                #pragma unroll
                for (int jj = 0; jj < 4; ++jj)
                    acc[ii][jj] = __builtin_amdgcn_mfma_f32_16x16x32_bf16(
                        af[ii], bf[jj], acc[ii][jj], 0, 0, 0);
            __builtin_amdgcn_s_setprio(0);
        }
    }

    float biasv[4];
    int mj[4];
    #pragma unroll
    for (int j = 0; j < 4; ++j) {
        const int c = col0 + wn * 64 + j * 16 + lr;
        if (BIAS) biasv[j] = bias[c];
        if (PM)   mj[j] = rm2[(long)bz * N + c];
    }
    float* Cf = (float*)C + (long)bz * sC;
    ushort_t* Ch = (ushort_t*)C + (long)bz * sC;

    #pragma unroll
    for (int i = 0; i < 4; ++i) {
        const int rg0 = row0 + wm * 64 + i * 16 + q * 4;   // first of 4 consecutive rows
        int mi4[4];
        if (RM || PM) {
            #pragma unroll
            for (int r = 0; r < 4; ++r) {
                const int row = rg0 + r;
                if (PM)      mi4[r] = rm1[(long)bz * M + row];
                else         mi4[r] = (row < Mhalf) ? rm1[row] : rm2[row - Mhalf];
            }
        }
        #pragma unroll
        for (int j = 0; j < 4; ++j) {
            const int c = col0 + wn * 64 + j * 16 + lr;
            ushort_t tp[4];
            #pragma unroll
            for (int r = 0; r < 4; ++r) {
                const int row = rg0 + r;
                float v = acc[i][j][r];
                if (BIAS) v += biasv[j];
                if (LRELU) v = lrelu_f(v);
                if (RM) v *= (float)mi4[r];
                if (PM) { if (!(mi4[r] && mj[j])) v += NEG_BIG; }
                const size_t a = (size_t)row * ldc + c;
                if (BF16OUT) Ch[a] = f2bf(v); else Cf[a] = v;
                if (TWOUT) tp[r] = f2bf(v);
            }
            if (TWOUT) {
                // slot-swapped: r1 batches -> slots 64..127, r2 batches -> 0..63
                const size_t ta = ((size_t)(((rg0 >> 9) + 64) & 127)) * 262144
                                + (size_t)c * 512 + (rg0 & 511);
                *reinterpret_cast<uint2*>(CT + ta) = *reinterpret_cast<uint2*>(tp);
            }
        }
    }
}

// ---------------------------------------------------------------------------
// fp32 -> bf16 convert for both inputs (y selects tensor)
__global__ __launch_bounds__(256)
void cvt2_f32_bf16(const float* __restrict__ a, const float* __restrict__ b,
                   ushort_t* __restrict__ oa, ushort_t* __restrict__ ob)
{
    const float* in = blockIdx.y ? b : a;
    ushort_t* out = blockIdx.y ? ob : oa;
    const long i = ((long)blockIdx.x * 256 + threadIdx.x) * 4;
    const float4 v = *reinterpret_cast<const float4*>(in + i);
    ushort_t o[4] = { f2bf(v.x), f2bf(v.y), f2bf(v.z), f2bf(v.w) };
    *reinterpret_cast<uint2*>(out + i) = *reinterpret_cast<uint2*>(o);
}

// all 4 weight transposes in one launch: fp32 [R,C] -> bf16 [C,R], z selects
__global__ __launch_bounds__(256)
void transpose_cvt4(const float* __restrict__ W1, const float* __restrict__ W2,
                    const float* __restrict__ Wc1, const float* __restrict__ Wc2,
                    ushort_t* __restrict__ W1t, ushort_t* __restrict__ W2t,
                    ushort_t* __restrict__ Wc1t, ushort_t* __restrict__ Wc2t)
{
    __shared__ float t[32][33];
    const int z = blockIdx.z;
    const float* in = (z == 0) ? W1 : (z == 1) ? W2 : (z == 2) ? Wc1 : Wc2;
    ushort_t* out   = (z == 0) ? W1t : (z == 1) ? W2t : (z == 2) ? Wc1t : Wc2t;
    const int R = (z == 2) ? 1024 : 512;
    const int C = 512;
    const int c0 = blockIdx.x * 32, r0 = blockIdx.y * 32;
    if (r0 >= R) return;
    const int tx = threadIdx.x & 31, ty = threadIdx.x >> 5;
    #pragma unroll
    for (int p = 0; p < 4; ++p)
        t[ty + p * 8][tx] = in[(size_t)(r0 + ty + p * 8) * C + c0 + tx];
    __syncthreads();
    #pragma unroll
    for (int p = 0; p < 4; ++p)
        out[(size_t)(c0 + ty + p * 8) * R + r0 + tx] = f2bf(t[tx][ty + p * 8]);
}

// one wave per row: max + 1/sum(exp)
__global__ __launch_bounds__(256)
void row_stats(const float* __restrict__ o, float* __restrict__ rmax,
               float* __restrict__ rsinv, int L)
{
    const int row  = blockIdx.x * 4 + (threadIdx.x >> 6);
    const int lane = threadIdx.x & 63;
    const float* p = o + (long)row * L;
    float m = -3.0e38f;
    for (int j = lane; j < L; j += 64) m = fmaxf(m, p[j]);
    #pragma unroll
    for (int off = 32; off > 0; off >>= 1) m = fmaxf(m, __shfl_xor(m, off));
    float s = 0.0f;
    for (int j = lane; j < L; j += 64) s += __expf(p[j] - m);
    #pragma unroll
    for (int off = 32; off > 0; off >>= 1) s += __shfl_xor(s, off);
    if (lane == 0) { rmax[row] = m; rsinv[row] = 1.0f / s; }
}

// column stats phase 1: each block scans 64 rows for 256 columns (split-K)
__global__ __launch_bounds__(256)
void col_part(const float* __restrict__ o, float* __restrict__ pm,
              float* __restrict__ ps, int L)
{
    const int b  = blockIdx.z;
    const int rc = blockIdx.y;
    const int j  = blockIdx.x * 256 + threadIdx.x;
    const float* p = o + (long)b * L * L + (long)rc * 64 * L + j;
    float m = -3.0e38f, s = 0.0f;
    #pragma unroll 4
    for (int i = 0; i < 64; ++i) {
        const float x = p[(long)i * L];
        const float mn = fmaxf(m, x);
        s = s * __expf(m - mn) + __expf(x - mn);
        m = mn;
    }
    const long idx = ((long)b * 8 + rc) * L + j;
    pm[idx] = m;
    ps[idx] = s;
}

// column stats phase 2: merge 8 partials per column
__global__ __launch_bounds__(256)
void col_combine(const float* __restrict__ pm, const float* __restrict__ ps,
                 float* __restrict__ cmax, float* __restrict__ csinv, int L)
{
    const int b = blockIdx.y;
    const int j = blockIdx.x * 256 + threadIdx.x;
    float mk[8], sk[8];
    #pragma unroll
    for (int k = 0; k < 8; ++k) {
        mk[k] = pm[((long)b * 8 + k) * L + j];
        sk[k] = ps[((long)b * 8 + k) * L + j];
    }
    float m = -3.0e38f;
    #pragma unroll
    for (int k = 0; k < 8; ++k) m = fmaxf(m, mk[k]);
    float s = 0.0f;
    #pragma unroll
    for (int k = 0; k < 8; ++k) s += sk[k] * __expf(mk[k] - m);
    cmax[b * L + j]  = m;
    csinv[b * L + j] = 1.0f / s;
}

// tiled: o1[b,i,j] = rowsm * mpos (bf16), o2T[b,j,i] = colsm * mpos (bf16)
__global__ __launch_bounds__(256)
void softmax_apply(const float* __restrict__ o,
                   ushort_t* __restrict__ o1, ushort_t* __restrict__ o2T,
                   const float* __restrict__ rmax, const float* __restrict__ rsinv,
                   const float* __restrict__ cmax, const float* __restrict__ csinv,
                   const int* __restrict__ m1, const int* __restrict__ m2)
{
    __shared__ ushort_t t[32][33];
    const int b = blockIdx.z;
    const long bo = (long)b * 512 * 512;
    const int j0 = blockIdx.x * 32, i0 = blockIdx.y * 32;
    const int tx = threadIdx.x & 31, ty = threadIdx.x >> 5;
    const int col = b * 512 + j0 + tx;
    const int mjv = m2[col];
    const float cm = cmax[col], cs = csinv[col];
    #pragma unroll
    for (int p = 0; p < 4; ++p) {
        const int i = i0 + ty + p * 8;
        const int row = b * 512 + i;
        const float x = o[bo + (long)i * 512 + j0 + tx];
        const float mp = (m1[row] != 0 && mjv != 0) ? 1.0f : 0.0f;
        o1[bo + (long)i * 512 + j0 + tx] = f2bf(__expf(x - rmax[row]) * rsinv[row] * mp);
        t[ty + p * 8][tx] = f2bf(__expf(x - cm) * cs * mp);
    }
    __syncthreads();
    #pragma unroll
    for (int p = 0; p < 4; ++p)
        o2T[bo + (long)(j0 + ty + p * 8) * 512 + i0 + tx] = t[tx][ty + p * 8];
}

// ---------------------------------------------------------------------------
extern "C" void kernel_launch(void* const* d_in, const int* in_sizes, int n_in,
                              void* d_out, int out_size, void* d_ws, size_t ws_size,
                              hipStream_t stream)
{
    const float* r1  = (const float*)d_in[0];
    const float* r2  = (const float*)d_in[1];
    const int*   m1  = (const int*)d_in[2];
    const int*   m2  = (const int*)d_in[3];
    const float* W1  = (const float*)d_in[4];
    const float* b1v = (const float*)d_in[5];
    const float* W2  = (const float*)d_in[6];
    const float* b2v = (const float*)d_in[7];
    const float* Wc1 = (const float*)d_in[8];
    const float* bc1 = (const float*)d_in[9];
    const float* Wc2 = (const float*)d_in[10];
    const float* bc2 = (const float*)d_in[11];
    float* out = (float*)d_out;

    constexpr int  Bn = 64, L = 512, D = 512;
    constexpr long CE = (long)Bn * L * D;  // 16,777,216 elements
    constexpr long S  = (long)L * L;       // 262,144
    constexpr int  NR = Bn * L;            // 32,768

    // d_out: 4 bf16 scratch slots (all dead before final fp32 writes)
    ushort_t* O    = (ushort_t*)d_out;
    ushort_t* r1b  = O;            // slot0: r1 bf16 (dead after GEMM 1)
    ushort_t* r2b  = O + CE;       // slot1: r2 bf16
    // After GEMM 2 (TWOUT slot-swapped): [slot0 | slot1] = [r2mT | r1mT],
    // uniform batch stride S from base O for the merged ctx GEMM.
    ushort_t* TT   = O;
    ushort_t* o1b  = O + 2 * CE;   // slot2: o1  (batches 0..63)
    // slot3 = o1b + CE = o2T (batches 64..127 of the same strided array)
    ushort_t* o2Tb = O + 3 * CE;

    // workspace
    char* wsb = (char*)d_ws;
    // R0 [0,4CE): h (2CE ushorts) -> obuf (CE floats) -> r1c‖r2c (2CE ushorts)
    ushort_t* hb   = (ushort_t*)wsb;
    float*    obuf = (float*)wsb;
    ushort_t* r1c  = (ushort_t*)wsb;
    // R1 [4CE,8CE): hc (compare hidden)
    ushort_t* hc   = (ushort_t*)(wsb + 4 * CE);
    // R2 [8CE,12CE): r1m ‖ r2m
    ushort_t* r1mb = (ushort_t*)(wsb + 8 * CE);
    ushort_t* r2mb = (ushort_t*)(wsb + 10 * CE);
    // R3 [12CE, ...): weights + stats
    ushort_t* W1t  = (ushort_t*)(wsb + 12 * CE);
    ushort_t* W2t  = W1t + 512 * 512;
    ushort_t* Wc1t = W2t + 512 * 512;            // [512,1024]
    ushort_t* Wc2t = Wc1t + 512 * 1024;
    float* rmaxv = (float*)(Wc2t + 512 * 512);
    float* rsinv = rmaxv + NR;
    float* cmaxv = rsinv + NR;
    float* csinv = cmaxv + NR;
    float* pmbuf = csinv + NR;                   // 8*512*64 floats
    float* psbuf = pmbuf + 8 * L * Bn;

    const dim3 blk(256);
    const dim3 blkG(1024);
    const dim3 gD2(D / 256, 2 * NR / 256, 1);    // combined dense: 2 x 256
    const dim3 gB(L / 256, L / 256, Bn);         // batched score: 2 x 2 x 64
    const dim3 gB2(L / 256, L / 256, 2 * Bn);    // merged ctx: 2 x 2 x 128

    // 0) convert inputs + weights
    cvt2_f32_bf16<<<dim3(CE / 1024, 2), blk, 0, stream>>>(r1, r2, r1b, r2b);
    transpose_cvt4<<<dim3(16, 32, 4), blk, 0, stream>>>(
        W1, W2, Wc1, Wc2, W1t, W2t, Wc1t, Wc2t);

    // 1) h = lrelu([r1;r2] @ W1 + b1)   M=65536
    gemm_nt<true,true,false,false,true,false><<<gD2, blkG, 0, stream>>>(
        r1b, r1b, D, D, D, W1t, D, b1v, nullptr, nullptr, hb, D,
        nullptr, 0, 2 * NR, D, D, 0, 0, 0);
    // 2) [r1m;r2m] = lrelu(h @ W2 + b2) * mask  + fused transposed copies
    gemm_nt<true,true,true,false,true,true><<<gD2, blkG, 0, stream>>>(
        hb, hb, D, D, D, W2t, D, b2v, m1, m2, r1mb, D,
        TT, NR, 2 * NR, D, D, 0, 0, 0);
    // 3) o = r1m @ r2m^T + pairmask  (batched fp32)
    gemm_nt<false,false,false,true,false,false><<<gB, blkG, 0, stream>>>(
        r1mb, r1mb, D, D, D, r2mb, D, nullptr, m1, m2, obuf, L,
        nullptr, 0, L, L, D, S, S, S);
    // 4) softmax stats
    row_stats<<<dim3(NR / 4), blk, 0, stream>>>(obuf, rmaxv, rsinv, L);
    col_part<<<dim3(L / 256, 8, Bn), blk, 0, stream>>>(obuf, pmbuf, psbuf, L);
    col_combine<<<dim3(L / 256, Bn), blk, 0, stream>>>(pmbuf, psbuf, cmaxv, csinv, L);
    // 5) o1 (bf16) + o2^T (bf16)
    softmax_apply<<<dim3(16, 16, Bn), blk, 0, stream>>>(
        obuf, o1b, o2Tb, rmaxv, rsinv, cmaxv, csinv, m1, m2);
    // 6+7 merged) z<64: r1_c = o1 @ r2m^T-slots ; z>=64: r2_c = o2T @ r1m^T-slots
    gemm_nt<false,false,false,false,true,false><<<gB2, blkG, 0, stream>>>(
        o1b, o1b, L, L, L, TT, L, nullptr, nullptr, nullptr, r1c, D,
        nullptr, 0, L, D, L, S, S, S);
    // 8) hc = lrelu(cat([r1m;r2m],[r1c;r2c]) @ Wc1 + bc1)  M=65536, K=1024
    gemm_nt<true,true,false,false,true,false><<<gD2, blkG, 0, stream>>>(
        r1mb, r1c, D, D, D, Wc1t, 2 * D, bc1, nullptr, nullptr, hc, D,
        nullptr, 0, 2 * NR, D, 2 * D, 0, 0, 0);
    // 9) [out1;out2] = lrelu(hc @ Wc2 + bc2) * mask  (fp32, full d_out)
    gemm_nt<true,true,true,false,false,false><<<gD2, blkG, 0, stream>>>(
        hc, hc, D, D, D, Wc2t, D, bc2, m1, m2, out, D,
        nullptr, NR, 2 * NR, D, D, 0, 0, 0);
}

// Round 7
// 599.588 us; speedup vs baseline: 1.0164x; 1.0164x over previous
//
#include <hip/hip_runtime.h>

#define LRELU_SLOPE 0.01f
#define NEG_BIG -1e10f

typedef unsigned short ushort_t;
typedef __bf16 bf16x8 __attribute__((ext_vector_type(8)));
typedef float f32x4 __attribute__((ext_vector_type(4)));

static __device__ __forceinline__ float lrelu_f(float x) {
    return x >= 0.0f ? x : LRELU_SLOPE * x;
}

static __device__ __forceinline__ ushort_t f2bf(float f) {
    unsigned int u = __float_as_uint(f);
    u += 0x7fffu + ((u >> 16) & 1u);
    return (ushort_t)(u >> 16);
}

static __device__ __forceinline__ void gld_lds16(const ushort_t* g, ushort_t* l) {
    __builtin_amdgcn_global_load_lds((const __attribute__((address_space(1))) void*)g,
                                     (__attribute__((address_space(3))) void*)l,
                                     16, 0, 0);
}

// ---------------------------------------------------------------------------
// NT bf16 MFMA GEMM: C[m,n] = epi( sum_k A[m,k] * B[n,k] )
// 256x128 tile, 8 waves (4M x 2N, 512 thr), BK=64; per-wave out 64x64.
// TWO-BLOCKS-PER-CU design (R5 post-mortem): R3-R5 all had 128KB LDS ->
// 1 block/CU -> the per-block serial chain (prologue stage, 8 short K-tiles
// each with a full staging drain, epilogue stores) had NOTHING to overlap
// with; schedule micro-structure (R4) and intra-block TLP (R5) were both
// null because the bubble is BLOCK-level. This kernel: single 48KB LDS
// buffer (2x48=96KB/CU) + ~124 unified regs/wave (60 VGPR + 64 acc AGPR,
// 4 waves/SIMD cap) -> 2 co-resident blocks/CU. Block A's stage drain is
// covered by block B's compute (m97/m114 implicit overlap, 874 TF proof).
// Loop: barrier (readers done) -> stage(T) -> vmcnt(0) -> barrier ->
//   2 k-phases {8 ds_read_b128, lgkmcnt(0), sched_barrier(0), setprio(1),
//   16 MFMA, setprio(0)}.
// setprio kept: two independent blocks sit at different phases (m191 regime).
// LDS XOR-swizzle: row r's 16B-chunk c stored at c ^ (r&7); staging inverse-
// permutes the per-lane GLOBAL source chunk (gld_lds dest linear, rule #21);
// ds_read applies the same XOR => conflict-free frag reads.
// XCD-aware tile remap (R0): lin -> (lin%8)*(nwg/8)+lin/8.
// RM mask: row < Mhalf ? rm1[row] : rm2[row-Mhalf]  (combined-M launches)
// PM mask: rm1[bz*M+row] && rm2[bz*N+col] else += NEG_BIG (batched score GEMM)
// TWOUT: also store bf16 transposed per-batch with slot swap:
//   CT[(((row>>9)+64)&127)*S + col*512 + (row&511)]  -> [r2mT | r1mT] order
// ---------------------------------------------------------------------------
template<bool BIAS, bool LRELU, bool RM, bool PM, bool BF16OUT, bool TWOUT>
__global__ __launch_bounds__(512, 4)
void gemm_nt(const ushort_t* __restrict__ A0, const ushort_t* __restrict__ A1,
             int Ksplit, int lda0, int lda1,
             const ushort_t* __restrict__ B, int ldb,
             const float* __restrict__ bias,
             const int* __restrict__ rm1, const int* __restrict__ rm2,
             void* __restrict__ C, int ldc,
             ushort_t* __restrict__ CT, int Mhalf,
             int M, int N, int K,
             long sA, long sB, long sC)
{
    __shared__ ushort_t As[256 * 64];   // 32 KB
    __shared__ ushort_t Bs[128 * 64];   // 16 KB

    // XCD-aware block remap (see header comment)
    const unsigned nbx = gridDim.x, nby = gridDim.y;
    unsigned lin = blockIdx.x + nbx * (blockIdx.y + nby * blockIdx.z);
    const unsigned nwg = nbx * nby * gridDim.z;
    if ((nwg & 7u) == 0u)
        lin = (lin & 7u) * (nwg >> 3) + (lin >> 3);
    const unsigned bxs = lin % nbx;
    const unsigned t1  = lin / nbx;
    const unsigned bys = t1 % nby;
    const unsigned bzs = t1 / nby;

    const int bz   = (int)bzs;
    const int tid  = threadIdx.x;
    const int w    = tid >> 6;         // 0..7
    const int lane = tid & 63;
    const int wm   = w >> 1;           // 0..3  (M quarter)
    const int wn   = w & 1;            // 0..1  (N half)
    const int row0 = (int)bys * 256;
    const int col0 = (int)bxs * 128;

    const ushort_t* Ab0 = A0 + (long)bz * sA;
    const ushort_t* Ab1 = A1 + (long)bz * sA;
    const ushort_t* Bb  = B  + (long)bz * sB;

    // staging: wave w covers A rows [w*32, w*32+32) (4 loads) and
    // B rows [w*16, w*16+16) (2 loads); 8 rows per gld_lds (64 lanes x 16B).
    // per-lane source chunk inverse-swizzled (row%8 == lane>>3).
    const int srA = w * 32 + (lane >> 3);
    const int srB = w * 16 + (lane >> 3);
    const int so  = (((lane & 7) ^ ((lane >> 3) & 7)) * 8);

    // fragment read addressing
    const int lr = lane & 15, q = lane >> 4;
    const int cx0 = ((q ^ (lr & 7)) * 8);          // kk=0 chunk, swizzled
    const int cx1 = (((q + 4) ^ (lr & 7)) * 8);    // kk=1 chunk, swizzled
    const int aRow = (wm * 64 + lr) * 64;
    const int bRow = (wn * 64 + lr) * 64;

    f32x4 acc[4][4] = {};

    auto stage = [&](int T) {
        const int k0g = T << 6;
        const ushort_t* Ap; int kk0, ldaP;
        if (k0g < Ksplit) { Ap = Ab0; kk0 = k0g;          ldaP = lda0; }
        else              { Ap = Ab1; kk0 = k0g - Ksplit; ldaP = lda1; }
        #pragma unroll
        for (int u = 0; u < 4; ++u)
            gld_lds16(Ap + (size_t)(row0 + srA + u * 8) * ldaP + kk0 + so,
                      As + (w * 32 + u * 8) * 64);
        #pragma unroll
        for (int u = 0; u < 2; ++u)
            gld_lds16(Bb + (size_t)(col0 + srB + u * 8) * ldb + k0g + so,
                      Bs + (w * 16 + u * 8) * 64);
    };

    const int NT = K >> 6;

    for (int T = 0; T < NT; ++T) {
        // barrier: all waves done READING the buffer from tile T-1
        __builtin_amdgcn_s_barrier();
        asm volatile("" ::: "memory");
        stage(T);
        asm volatile("s_waitcnt vmcnt(0)" ::: "memory");
        __builtin_amdgcn_s_barrier();
        asm volatile("" ::: "memory");

        #pragma unroll
        for (int kk = 0; kk < 2; ++kk) {
            const int cx = kk ? cx1 : cx0;
            bf16x8 af[4], bf[4];
            #pragma unroll
            for (int ii = 0; ii < 4; ++ii)
                af[ii] = *reinterpret_cast<const bf16x8*>(&As[aRow + (ii * 16) * 64 + cx]);
            #pragma unroll
            for (int jj = 0; jj < 4; ++jj)
                bf[jj] = *reinterpret_cast<const bf16x8*>(&Bs[bRow + (jj * 16) * 64 + cx]);
            asm volatile("s_waitcnt lgkmcnt(0)" ::: "memory");
            __builtin_amdgcn_sched_barrier(0);
            __builtin_amdgcn_s_setprio(1);
            #pragma unroll
            for (int ii = 0; ii < 4; ++ii)
                #pragma unroll
                for (int jj = 0; jj < 4; ++jj)
                    acc[ii][jj] = __builtin_amdgcn_mfma_f32_16x16x32_bf16(
                        af[ii], bf[jj], acc[ii][jj], 0, 0, 0);
            __builtin_amdgcn_s_setprio(0);
        }
    }

    float biasv[4];
    int mj[4];
    #pragma unroll
    for (int j = 0; j < 4; ++j) {
        const int c = col0 + wn * 64 + j * 16 + lr;
        if (BIAS) biasv[j] = bias[c];
        if (PM)   mj[j] = rm2[(long)bz * N + c];
    }
    float* Cf = (float*)C + (long)bz * sC;
    ushort_t* Ch = (ushort_t*)C + (long)bz * sC;

    #pragma unroll
    for (int i = 0; i < 4; ++i) {
        const int rg0 = row0 + wm * 64 + i * 16 + q * 4;   // first of 4 consecutive rows
        int mi4[4];
        if (RM || PM) {
            #pragma unroll
            for (int r = 0; r < 4; ++r) {
                const int row = rg0 + r;
                if (PM)      mi4[r] = rm1[(long)bz * M + row];
                else         mi4[r] = (row < Mhalf) ? rm1[row] : rm2[row - Mhalf];
            }
        }
        #pragma unroll
        for (int j = 0; j < 4; ++j) {
            const int c = col0 + wn * 64 + j * 16 + lr;
            ushort_t tp[4];
            #pragma unroll
            for (int r = 0; r < 4; ++r) {
                const int row = rg0 + r;
                float v = acc[i][j][r];
                if (BIAS) v += biasv[j];
                if (LRELU) v = lrelu_f(v);
                if (RM) v *= (float)mi4[r];
                if (PM) { if (!(mi4[r] && mj[j])) v += NEG_BIG; }
                const size_t a = (size_t)row * ldc + c;
                if (BF16OUT) Ch[a] = f2bf(v); else Cf[a] = v;
                if (TWOUT) tp[r] = f2bf(v);
            }
            if (TWOUT) {
                // slot-swapped: r1 batches -> slots 64..127, r2 batches -> 0..63
                const size_t ta = ((size_t)(((rg0 >> 9) + 64) & 127)) * 262144
                                + (size_t)c * 512 + (rg0 & 511);
                *reinterpret_cast<uint2*>(CT + ta) = *reinterpret_cast<uint2*>(tp);
            }
        }
    }
}

// ---------------------------------------------------------------------------
// fp32 -> bf16 convert for both inputs (y selects tensor)
__global__ __launch_bounds__(256)
void cvt2_f32_bf16(const float* __restrict__ a, const float* __restrict__ b,
                   ushort_t* __restrict__ oa, ushort_t* __restrict__ ob)
{
    const float* in = blockIdx.y ? b : a;
    ushort_t* out = blockIdx.y ? ob : oa;
    const long i = ((long)blockIdx.x * 256 + threadIdx.x) * 4;
    const float4 v = *reinterpret_cast<const float4*>(in + i);
    ushort_t o[4] = { f2bf(v.x), f2bf(v.y), f2bf(v.z), f2bf(v.w) };
    *reinterpret_cast<uint2*>(out + i) = *reinterpret_cast<uint2*>(o);
}

// all 4 weight transposes in one launch: fp32 [R,C] -> bf16 [C,R], z selects
__global__ __launch_bounds__(256)
void transpose_cvt4(const float* __restrict__ W1, const float* __restrict__ W2,
                    const float* __restrict__ Wc1, const float* __restrict__ Wc2,
                    ushort_t* __restrict__ W1t, ushort_t* __restrict__ W2t,
                    ushort_t* __restrict__ Wc1t, ushort_t* __restrict__ Wc2t)
{
    __shared__ float t[32][33];
    const int z = blockIdx.z;
    const float* in = (z == 0) ? W1 : (z == 1) ? W2 : (z == 2) ? Wc1 : Wc2;
    ushort_t* out   = (z == 0) ? W1t : (z == 1) ? W2t : (z == 2) ? Wc1t : Wc2t;
    const int R = (z == 2) ? 1024 : 512;
    const int C = 512;
    const int c0 = blockIdx.x * 32, r0 = blockIdx.y * 32;
    if (r0 >= R) return;
    const int tx = threadIdx.x & 31, ty = threadIdx.x >> 5;
    #pragma unroll
    for (int p = 0; p < 4; ++p)
        t[ty + p * 8][tx] = in[(size_t)(r0 + ty + p * 8) * C + c0 + tx];
    __syncthreads();
    #pragma unroll
    for (int p = 0; p < 4; ++p)
        out[(size_t)(c0 + ty + p * 8) * R + r0 + tx] = f2bf(t[tx][ty + p * 8]);
}

// one wave per row: max + 1/sum(exp)
__global__ __launch_bounds__(256)
void row_stats(const float* __restrict__ o, float* __restrict__ rmax,
               float* __restrict__ rsinv, int L)
{
    const int row  = blockIdx.x * 4 + (threadIdx.x >> 6);
    const int lane = threadIdx.x & 63;
    const float* p = o + (long)row * L;
    float m = -3.0e38f;
    for (int j = lane; j < L; j += 64) m = fmaxf(m, p[j]);
    #pragma unroll
    for (int off = 32; off > 0; off >>= 1) m = fmaxf(m, __shfl_xor(m, off));
    float s = 0.0f;
    for (int j = lane; j < L; j += 64) s += __expf(p[j] - m);
    #pragma unroll
    for (int off = 32; off > 0; off >>= 1) s += __shfl_xor(s, off);
    if (lane == 0) { rmax[row] = m; rsinv[row] = 1.0f / s; }
}

// column stats phase 1: each block scans 64 rows for 256 columns (split-K)
__global__ __launch_bounds__(256)
void col_part(const float* __restrict__ o, float* __restrict__ pm,
              float* __restrict__ ps, int L)
{
    const int b  = blockIdx.z;
    const int rc = blockIdx.y;
    const int j  = blockIdx.x * 256 + threadIdx.x;
    const float* p = o + (long)b * L * L + (long)rc * 64 * L + j;
    float m = -3.0e38f, s = 0.0f;
    #pragma unroll 4
    for (int i = 0; i < 64; ++i) {
        const float x = p[(long)i * L];
        const float mn = fmaxf(m, x);
        s = s * __expf(m - mn) + __expf(x - mn);
        m = mn;
    }
    const long idx = ((long)b * 8 + rc) * L + j;
    pm[idx] = m;
    ps[idx] = s;
}

// column stats phase 2: merge 8 partials per column
__global__ __launch_bounds__(256)
void col_combine(const float* __restrict__ pm, const float* __restrict__ ps,
                 float* __restrict__ cmax, float* __restrict__ csinv, int L)
{
    const int b = blockIdx.y;
    const int j = blockIdx.x * 256 + threadIdx.x;
    float mk[8], sk[8];
    #pragma unroll
    for (int k = 0; k < 8; ++k) {
        mk[k] = pm[((long)b * 8 + k) * L + j];
        sk[k] = ps[((long)b * 8 + k) * L + j];
    }
    float m = -3.0e38f;
    #pragma unroll
    for (int k = 0; k < 8; ++k) m = fmaxf(m, mk[k]);
    float s = 0.0f;
    #pragma unroll
    for (int k = 0; k < 8; ++k) s += sk[k] * __expf(mk[k] - m);
    cmax[b * L + j]  = m;
    csinv[b * L + j] = 1.0f / s;
}

// tiled: o1[b,i,j] = rowsm * mpos (bf16), o2T[b,j,i] = colsm * mpos (bf16)
__global__ __launch_bounds__(256)
void softmax_apply(const float* __restrict__ o,
                   ushort_t* __restrict__ o1, ushort_t* __restrict__ o2T,
                   const float* __restrict__ rmax, const float* __restrict__ rsinv,
                   const float* __restrict__ cmax, const float* __restrict__ csinv,
                   const int* __restrict__ m1, const int* __restrict__ m2)
{
    __shared__ ushort_t t[32][33];
    const int b = blockIdx.z;
    const long bo = (long)b * 512 * 512;
    const int j0 = blockIdx.x * 32, i0 = blockIdx.y * 32;
    const int tx = threadIdx.x & 31, ty = threadIdx.x >> 5;
    const int col = b * 512 + j0 + tx;
    const int mjv = m2[col];
    const float cm = cmax[col], cs = csinv[col];
    #pragma unroll
    for (int p = 0; p < 4; ++p) {
        const int i = i0 + ty + p * 8;
        const int row = b * 512 + i;
        const float x = o[bo + (long)i * 512 + j0 + tx];
        const float mp = (m1[row] != 0 && mjv != 0) ? 1.0f : 0.0f;
        o1[bo + (long)i * 512 + j0 + tx] = f2bf(__expf(x - rmax[row]) * rsinv[row] * mp);
        t[ty + p * 8][tx] = f2bf(__expf(x - cm) * cs * mp);
    }
    __syncthreads();
    #pragma unroll
    for (int p = 0; p < 4; ++p)
        o2T[bo + (long)(j0 + ty + p * 8) * 512 + i0 + tx] = t[tx][ty + p * 8];
}

// ---------------------------------------------------------------------------
extern "C" void kernel_launch(void* const* d_in, const int* in_sizes, int n_in,
                              void* d_out, int out_size, void* d_ws, size_t ws_size,
                              hipStream_t stream)
{
    const float* r1  = (const float*)d_in[0];
    const float* r2  = (const float*)d_in[1];
    const int*   m1  = (const int*)d_in[2];
    const int*   m2  = (const int*)d_in[3];
    const float* W1  = (const float*)d_in[4];
    const float* b1v = (const float*)d_in[5];
    const float* W2  = (const float*)d_in[6];
    const float* b2v = (const float*)d_in[7];
    const float* Wc1 = (const float*)d_in[8];
    const float* bc1 = (const float*)d_in[9];
    const float* Wc2 = (const float*)d_in[10];
    const float* bc2 = (const float*)d_in[11];
    float* out = (float*)d_out;

    constexpr int  Bn = 64, L = 512, D = 512;
    constexpr long CE = (long)Bn * L * D;  // 16,777,216 elements
    constexpr long S  = (long)L * L;       // 262,144
    constexpr int  NR = Bn * L;            // 32,768

    // d_out: 4 bf16 scratch slots (all dead before final fp32 writes)
    ushort_t* O    = (ushort_t*)d_out;
    ushort_t* r1b  = O;            // slot0: r1 bf16 (dead after GEMM 1)
    ushort_t* r2b  = O + CE;       // slot1: r2 bf16
    // After GEMM 2 (TWOUT slot-swapped): [slot0 | slot1] = [r2mT | r1mT],
    // uniform batch stride S from base O for the merged ctx GEMM.
    ushort_t* TT   = O;
    ushort_t* o1b  = O + 2 * CE;   // slot2: o1  (batches 0..63)
    // slot3 = o1b + CE = o2T (batches 64..127 of the same strided array)
    ushort_t* o2Tb = O + 3 * CE;

    // workspace
    char* wsb = (char*)d_ws;
    // R0 [0,4CE): h (2CE ushorts) -> obuf (CE floats) -> r1c‖r2c (2CE ushorts)
    ushort_t* hb   = (ushort_t*)wsb;
    float*    obuf = (float*)wsb;
    ushort_t* r1c  = (ushort_t*)wsb;
    // R1 [4CE,8CE): hc (compare hidden)
    ushort_t* hc   = (ushort_t*)(wsb + 4 * CE);
    // R2 [8CE,12CE): r1m ‖ r2m
    ushort_t* r1mb = (ushort_t*)(wsb + 8 * CE);
    ushort_t* r2mb = (ushort_t*)(wsb + 10 * CE);
    // R3 [12CE, ...): weights + stats
    ushort_t* W1t  = (ushort_t*)(wsb + 12 * CE);
    ushort_t* W2t  = W1t + 512 * 512;
    ushort_t* Wc1t = W2t + 512 * 512;            // [512,1024]
    ushort_t* Wc2t = Wc1t + 512 * 1024;
    float* rmaxv = (float*)(Wc2t + 512 * 512);
    float* rsinv = rmaxv + NR;
    float* cmaxv = rsinv + NR;
    float* csinv = cmaxv + NR;
    float* pmbuf = csinv + NR;                   // 8*512*64 floats
    float* psbuf = pmbuf + 8 * L * Bn;

    const dim3 blk(256);
    const dim3 blkG(512);
    const dim3 gD2(D / 128, 2 * NR / 256, 1);    // combined dense: 4 x 256
    const dim3 gB(L / 128, L / 256, Bn);         // batched score: 4 x 2 x 64
    const dim3 gB2(L / 128, L / 256, 2 * Bn);    // merged ctx: 4 x 2 x 128

    // 0) convert inputs + weights
    cvt2_f32_bf16<<<dim3(CE / 1024, 2), blk, 0, stream>>>(r1, r2, r1b, r2b);
    transpose_cvt4<<<dim3(16, 32, 4), blk, 0, stream>>>(
        W1, W2, Wc1, Wc2, W1t, W2t, Wc1t, Wc2t);

    // 1) h = lrelu([r1;r2] @ W1 + b1)   M=65536
    gemm_nt<true,true,false,false,true,false><<<gD2, blkG, 0, stream>>>(
        r1b, r1b, D, D, D, W1t, D, b1v, nullptr, nullptr, hb, D,
        nullptr, 0, 2 * NR, D, D, 0, 0, 0);
    // 2) [r1m;r2m] = lrelu(h @ W2 + b2) * mask  + fused transposed copies
    gemm_nt<true,true,true,false,true,true><<<gD2, blkG, 0, stream>>>(
        hb, hb, D, D, D, W2t, D, b2v, m1, m2, r1mb, D,
        TT, NR, 2 * NR, D, D, 0, 0, 0);
    // 3) o = r1m @ r2m^T + pairmask  (batched fp32)
    gemm_nt<false,false,false,true,false,false><<<gB, blkG, 0, stream>>>(
        r1mb, r1mb, D, D, D, r2mb, D, nullptr, m1, m2, obuf, L,
        nullptr, 0, L, L, D, S, S, S);
    // 4) softmax stats
    row_stats<<<dim3(NR / 4), blk, 0, stream>>>(obuf, rmaxv, rsinv, L);
    col_part<<<dim3(L / 256, 8, Bn), blk, 0, stream>>>(obuf, pmbuf, psbuf, L);
    col_combine<<<dim3(L / 256, Bn), blk, 0, stream>>>(pmbuf, psbuf, cmaxv, csinv, L);
    // 5) o1 (bf16) + o2^T (bf16)
    softmax_apply<<<dim3(16, 16, Bn), blk, 0, stream>>>(
        obuf, o1b, o2Tb, rmaxv, rsinv, cmaxv, csinv, m1, m2);
    // 6+7 merged) z<64: r1_c = o1 @ r2m^T-slots ; z>=64: r2_c = o2T @ r1m^T-slots
    gemm_nt<false,false,false,false,true,false><<<gB2, blkG, 0, stream>>>(
        o1b, o1b, L, L, L, TT, L, nullptr, nullptr, nullptr, r1c, D,
        nullptr, 0, L, D, L, S, S, S);
    // 8) hc = lrelu(cat([r1m;r2m],[r1c;r2c]) @ Wc1 + bc1)  M=65536, K=1024
    gemm_nt<true,true,false,false,true,false><<<gD2, blkG, 0, stream>>>(
        r1mb, r1c, D, D, D, Wc1t, 2 * D, bc1, nullptr, nullptr, hc, D,
        nullptr, 0, 2 * NR, D, 2 * D, 0, 0, 0);
    // 9) [out1;out2] = lrelu(hc @ Wc2 + bc2) * mask  (fp32, full d_out)
    gemm_nt<true,true,true,false,false,false><<<gD2, blkG, 0, stream>>>(
        hc, hc, D, D, D, Wc2t, D, bc2, m1, m2, out, D,
        nullptr, NR, 2 * NR, D, D, 0, 0, 0);
}